// Round 1
// baseline (320.763 us; speedup 1.0000x reference)
//
#include <hip/hip_runtime.h>

#define B_SZ 8192
#define C_SZ 1024
#define NCLS 100
#define INV_T 0.25f
#define TI 8
#define TJ 8

typedef unsigned int uint32;

// round-to-nearest-even fp32 -> bf16 (inputs are positive, finite)
__device__ __forceinline__ unsigned short f2bf(float f) {
    uint32 u = __float_as_uint(f);
    u = u + 0x7fffu + ((u >> 16) & 1u);
    return (unsigned short)(u >> 16);
}

__global__ __launch_bounds__(128) void init_kernel(int* counts, float* accum) {
    counts[threadIdx.x] = 0;
    if (threadIdx.x == 0) accum[0] = 0.0f;
}

// One block per row: softmax(x/T)+1e-8 -> bf16 probs; t[row] = mean(p*log p) in fp32.
__global__ __launch_bounds__(256) void softmax_kernel(const float* __restrict__ x,
                                                      uint32* __restrict__ probs_bf,
                                                      float* __restrict__ t) {
    int row = blockIdx.x;
    int tid = threadIdx.x;
    const float4* xr = (const float4*)(x + (size_t)row * C_SZ);
    float4 v = xr[tid];
    v.x *= INV_T; v.y *= INV_T; v.z *= INV_T; v.w *= INV_T;

    __shared__ float red[12];
    int wid = tid >> 6;

    float m = fmaxf(fmaxf(v.x, v.y), fmaxf(v.z, v.w));
    #pragma unroll
    for (int o = 32; o >= 1; o >>= 1) m = fmaxf(m, __shfl_xor(m, o, 64));
    if ((tid & 63) == 0) red[wid] = m;
    __syncthreads();
    m = fmaxf(fmaxf(red[0], red[1]), fmaxf(red[2], red[3]));

    float4 e;
    e.x = expf(v.x - m); e.y = expf(v.y - m);
    e.z = expf(v.z - m); e.w = expf(v.w - m);
    float s = (e.x + e.y) + (e.z + e.w);
    #pragma unroll
    for (int o = 32; o >= 1; o >>= 1) s += __shfl_xor(s, o, 64);
    if ((tid & 63) == 0) red[4 + wid] = s;
    __syncthreads();
    float Z = (red[4] + red[5]) + (red[6] + red[7]);
    float rZ = 1.0f / Z;

    float4 p;
    p.x = e.x * rZ + 1e-8f; p.y = e.y * rZ + 1e-8f;
    p.z = e.z * rZ + 1e-8f; p.w = e.w * rZ + 1e-8f;

    uint2 packed;
    packed.x = ((uint32)f2bf(p.y) << 16) | (uint32)f2bf(p.x);
    packed.y = ((uint32)f2bf(p.w) << 16) | (uint32)f2bf(p.z);
    ((uint2*)(probs_bf + (size_t)row * (C_SZ / 2)))[tid] = packed;

    float pl = p.x * logf(p.x) + p.y * logf(p.y) + p.z * logf(p.z) + p.w * logf(p.w);
    #pragma unroll
    for (int o = 32; o >= 1; o >>= 1) pl += __shfl_xor(pl, o, 64);
    if ((tid & 63) == 0) red[8 + wid] = pl;
    __syncthreads();
    if (tid == 0)
        t[row] = ((red[8] + red[9]) + (red[10] + red[11])) * (1.0f / C_SZ);
}

__global__ __launch_bounds__(256) void bucket_kernel(const int* __restrict__ target,
                                                     int* counts, int* lists) {
    int r = blockIdx.x * 256 + threadIdx.x;
    int lbl = target[r];
    int slot = atomicAdd(&counts[lbl], 1);
    lists[lbl * B_SZ + slot] = r;
}

// Grid-stride over work items = (class k, i-tile ti, j-tile tj), tiles of 8x8 pairs.
// 16 rows staged in LDS as packed bf16; fp32 accumulate of dot products.
__global__ __launch_bounds__(256) void pair_kernel(const uint32* __restrict__ probs_bf,
                                                   const float* __restrict__ t,
                                                   const int* __restrict__ counts,
                                                   const int* __restrict__ lists,
                                                   float* __restrict__ accum) {
    __shared__ uint32 rows[16][512];   // 16 rows x 1024 bf16 (packed pairs) = 32 KB
    __shared__ int s_counts[NCLS];
    __shared__ int s_rowid[16];
    __shared__ float s_tj[TJ];
    __shared__ float s_part[8];

    int tid = threadIdx.x;
    for (int i = tid; i < NCLS; i += 256) s_counts[i] = counts[i];
    __syncthreads();

    for (long long item = blockIdx.x; ; item += gridDim.x) {
        // map item -> (k, ti, tj)
        int k = -1, ti = 0, tj = 0;
        long long rem = item;
        for (int c = 0; c < NCLS; c++) {
            int m = s_counts[c];
            int nt = (m + TI - 1) / TI;
            long long it = (long long)nt * nt;
            if (rem < it) { k = c; ti = (int)(rem / nt); tj = (int)(rem % nt); break; }
            rem -= it;
        }
        if (k < 0) break;
        int m = s_counts[k];
        __syncthreads();   // previous iteration fully done with LDS

        if (tid < 16) {
            int which = (tid < TI) ? (ti * TI + tid) : (tj * TJ + (tid - TI));
            int rid = (which < m) ? lists[k * B_SZ + which] : -1;
            s_rowid[tid] = rid;
            if (tid >= TI) s_tj[tid - TI] = (rid >= 0) ? t[rid] : 0.0f;
        }
        __syncthreads();

        // stage 16 rows: 16 * 128 uint4 loads, 8 per thread
        #pragma unroll
        for (int step = 0; step < 8; step++) {
            int idx = tid + step * 256;
            int r = idx >> 7;
            int q = idx & 127;
            int rid = s_rowid[r];
            uint4 vv = make_uint4(0u, 0u, 0u, 0u);
            if (rid >= 0) vv = ((const uint4*)(probs_bf + (size_t)rid * (C_SZ / 2)))[q];
            ((uint4*)&rows[r][0])[q] = vv;
        }
        __syncthreads();

        // thread (ii, tc): i-row ii, column strip; register-cache 32 cols of p_i
        int ii = tid >> 5;
        int tc = tid & 31;
        int my_rid = s_rowid[ii];
        float pi[32];
        #pragma unroll
        for (int w = 0; w < 8; w++) {
            uint2 u = *(const uint2*)&rows[ii][w * 64 + tc * 2];
            pi[w * 4 + 0] = __uint_as_float(u.x << 16);
            pi[w * 4 + 1] = __uint_as_float(u.x & 0xffff0000u);
            pi[w * 4 + 2] = __uint_as_float(u.y << 16);
            pi[w * 4 + 3] = __uint_as_float(u.y & 0xffff0000u);
        }

        float local = 0.0f;
        #pragma unroll
        for (int jj = 0; jj < TJ; jj++) {
            float acc = 0.0f;
            #pragma unroll
            for (int w = 0; w < 8; w++) {
                uint2 u = *(const uint2*)&rows[8 + jj][w * 64 + tc * 2];
                acc += pi[w * 4 + 0] * __uint_as_float(u.x << 16);
                acc += pi[w * 4 + 1] * __uint_as_float(u.x & 0xffff0000u);
                acc += pi[w * 4 + 2] * __uint_as_float(u.y << 16);
                acc += pi[w * 4 + 3] * __uint_as_float(u.y & 0xffff0000u);
            }
            #pragma unroll
            for (int o = 16; o >= 1; o >>= 1) acc += __shfl_xor(acc, o, 64);
            int jr = s_rowid[TI + jj];
            if (tc == 0 && my_rid >= 0 && jr >= 0 && jr != my_rid) {
                float kl = s_tj[jj] - acc * (1.0f / C_SZ);
                local += kl * kl;
            }
        }

        if (tc == 0) s_part[ii] = local;
        __syncthreads();
        if (tid == 0) {
            float ssum = 0.0f;
            #pragma unroll
            for (int z = 0; z < 8; z++) ssum += s_part[z];
            atomicAdd(accum, ssum);
        }
    }
}

__global__ void finalize_kernel(const float* __restrict__ accum, float* __restrict__ out) {
    out[0] = accum[0] * (1.0f / B_SZ);
}

extern "C" void kernel_launch(void* const* d_in, const int* in_sizes, int n_in,
                              void* d_out, int out_size, void* d_ws, size_t ws_size,
                              hipStream_t stream) {
    const float* x = (const float*)d_in[0];
    const int* target = (const int*)d_in[1];
    float* out = (float*)d_out;

    char* ws = (char*)d_ws;
    uint32* probs_bf = (uint32*)ws;                                   // 16 MB (B*C bf16)
    float* t = (float*)(ws + (size_t)B_SZ * C_SZ * 2);                // 32 KB
    int* counts = (int*)(ws + (size_t)B_SZ * C_SZ * 2 + B_SZ * 4);    // 512 B
    int* lists = counts + 128;                                        // 3.2 MB
    float* accum = (float*)(lists + (size_t)NCLS * B_SZ);             // 4 B

    init_kernel<<<1, 128, 0, stream>>>(counts, accum);
    softmax_kernel<<<B_SZ, 256, 0, stream>>>(x, probs_bf, t);
    bucket_kernel<<<B_SZ / 256, 256, 0, stream>>>(target, counts, lists);
    pair_kernel<<<4096, 256, 0, stream>>>(probs_bf, t, counts, lists, accum);
    finalize_kernel<<<1, 1, 0, stream>>>(accum, out);
}

// Round 2
// 122.779 us; speedup vs baseline: 2.6125x; 2.6125x over previous
//
#include <hip/hip_runtime.h>

#define B_SZ 8192
#define C_SZ 1024
#define NCLS 100
#define INV_T 0.25f

typedef unsigned int uint32;

using bf16x8 = __attribute__((ext_vector_type(8))) short;
using f32x16 = __attribute__((ext_vector_type(16))) float;

// round-to-nearest-even fp32 -> bf16 (inputs are positive, finite)
__device__ __forceinline__ unsigned short f2bf(float f) {
    uint32 u = __float_as_uint(f);
    u = u + 0x7fffu + ((u >> 16) & 1u);
    return (unsigned short)(u >> 16);
}

__global__ __launch_bounds__(128) void init_kernel(int* counts, int* nitems, float* accum) {
    counts[threadIdx.x] = 0;
    if (threadIdx.x == 0) { nitems[0] = 0; accum[0] = 0.0f; }
}

// One block per row: softmax(x/T)+1e-8 -> bf16 probs; t[row] = mean(p*log p) in fp32.
__global__ __launch_bounds__(256) void softmax_kernel(const float* __restrict__ x,
                                                      uint32* __restrict__ probs_bf,
                                                      float* __restrict__ t) {
    int row = blockIdx.x;
    int tid = threadIdx.x;
    const float4* xr = (const float4*)(x + (size_t)row * C_SZ);
    float4 v = xr[tid];
    v.x *= INV_T; v.y *= INV_T; v.z *= INV_T; v.w *= INV_T;

    __shared__ float red[12];
    int wid = tid >> 6;

    float m = fmaxf(fmaxf(v.x, v.y), fmaxf(v.z, v.w));
    #pragma unroll
    for (int o = 32; o >= 1; o >>= 1) m = fmaxf(m, __shfl_xor(m, o, 64));
    if ((tid & 63) == 0) red[wid] = m;
    __syncthreads();
    m = fmaxf(fmaxf(red[0], red[1]), fmaxf(red[2], red[3]));

    float4 e;
    e.x = __expf(v.x - m); e.y = __expf(v.y - m);
    e.z = __expf(v.z - m); e.w = __expf(v.w - m);
    float s = (e.x + e.y) + (e.z + e.w);
    #pragma unroll
    for (int o = 32; o >= 1; o >>= 1) s += __shfl_xor(s, o, 64);
    if ((tid & 63) == 0) red[4 + wid] = s;
    __syncthreads();
    float Z = (red[4] + red[5]) + (red[6] + red[7]);
    float rZ = 1.0f / Z;

    float4 p;
    p.x = e.x * rZ + 1e-8f; p.y = e.y * rZ + 1e-8f;
    p.z = e.z * rZ + 1e-8f; p.w = e.w * rZ + 1e-8f;

    uint2 packed;
    packed.x = ((uint32)f2bf(p.y) << 16) | (uint32)f2bf(p.x);
    packed.y = ((uint32)f2bf(p.w) << 16) | (uint32)f2bf(p.z);
    ((uint2*)(probs_bf + (size_t)row * (C_SZ / 2)))[tid] = packed;

    float pl = p.x * __logf(p.x) + p.y * __logf(p.y) +
               p.z * __logf(p.z) + p.w * __logf(p.w);
    #pragma unroll
    for (int o = 32; o >= 1; o >>= 1) pl += __shfl_xor(pl, o, 64);
    if ((tid & 63) == 0) red[8 + wid] = pl;
    __syncthreads();
    if (tid == 0)
        t[row] = ((red[8] + red[9]) + (red[10] + red[11])) * (1.0f / C_SZ);
}

__global__ __launch_bounds__(256) void bucket_kernel(const int* __restrict__ target,
                                                     int* counts, int* lists) {
    int r = blockIdx.x * 256 + threadIdx.x;
    int lbl = target[r];
    int slot = atomicAdd(&counts[lbl], 1);
    lists[lbl * B_SZ + slot] = r;
}

// One thread per class: append its (k, ti, tj) 32x32 output tiles to the item table.
__global__ __launch_bounds__(128) void setup_items_kernel(const int* __restrict__ counts,
                                                          int* nitems, int* items) {
    int k = threadIdx.x;
    if (k >= NCLS) return;
    int m = counts[k];
    int nt = (m + 31) >> 5;
    int cnt = nt * nt;
    if (cnt == 0) return;
    int base = atomicAdd(nitems, cnt);
    int z = 0;
    for (int ti = 0; ti < nt; ti++)
        for (int tj = 0; tj < nt; tj++)
            items[base + z++] = k | (ti << 8) | (tj << 20);
}

// One wave per 32x32 output tile of a class Gram matrix. K-loop over C=1024 in
// chunks of 128 cols; A/B strips staged in LDS as XOR-swizzled 16B chunks so
// both the staging ds_write_b128 and the fragment ds_read_b128 are conflict-free.
// mfma_f32_32x32x16_bf16: A/B frag = lane (l&31)=row, k = (l>>5)*8 + j ->
// 16B contiguous per lane. D: col=lane&31, row=(reg&3)+8*(reg>>2)+4*(lane>>5).
__global__ __launch_bounds__(64) void pair_kernel(const uint4* __restrict__ probs,
                                                  const float* __restrict__ t,
                                                  const int* __restrict__ counts,
                                                  const int* __restrict__ lists,
                                                  const int* __restrict__ nitems,
                                                  const int* __restrict__ items,
                                                  float* __restrict__ accum) {
    __shared__ uint4 tile[2 * 32 * 16];   // 2 strips x 32 rows x 16 chunks = 16 KB
    __shared__ int s_rid[2][32];
    __shared__ float s_tB[32];

    int tid = threadIdx.x;
    int NI = nitems[0];

    for (int it = blockIdx.x; it < NI; it += gridDim.x) {
        int pk = items[it];
        int k = pk & 255;
        int ti = (pk >> 8) & 0xfff;
        int tj = pk >> 20;
        int m = counts[k];

        __syncthreads();   // previous item fully done with LDS
        if (tid < 32) {
            int which = tj * 32 + tid;
            int w = which < m ? which : m - 1;   // clamp: masked in epilogue
            int rid = lists[k * B_SZ + w];
            s_rid[1][tid] = rid;
            s_tB[tid] = t[rid];
        } else {
            int l = tid - 32;
            int which = ti * 32 + l;
            int w = which < m ? which : m - 1;
            s_rid[0][l] = lists[k * B_SZ + w];
        }
        __syncthreads();

        f32x16 acc = {};
        #pragma unroll 1
        for (int ki = 0; ki < 8; ki++) {
            // stage: 1024 16B chunks (A strip then B strip), 16 per thread
            #pragma unroll
            for (int s = 0; s < 16; s++) {
                int idx = tid + s * 64;
                int strip = idx >> 9;
                int r = (idx >> 4) & 31;
                int c = idx & 15;
                int rid = s_rid[strip][r];
                uint4 v = probs[(size_t)rid * (C_SZ / 8) + ki * 16 + c];
                tile[((strip * 32 + r) << 4) + (c ^ (r & 15))] = v;
            }
            __syncthreads();
            int half = tid >> 5;
            int r = tid & 31;
            #pragma unroll
            for (int i = 0; i < 8; i++) {
                int ch = (2 * i + half) ^ (r & 15);
                bf16x8 a = *(const bf16x8*)&tile[(r << 4) + ch];
                bf16x8 b = *(const bf16x8*)&tile[((32 + r) << 4) + ch];
                acc = __builtin_amdgcn_mfma_f32_32x32x16_bf16(a, b, acc, 0, 0, 0);
            }
            __syncthreads();
        }

        // epilogue: kl[i,j] = t[j] - dot/C; add kl^2 for valid i!=j
        int jl = tj * 32 + (tid & 31);
        bool jv = jl < m;
        float tjv = s_tB[tid & 31];
        float local = 0.0f;
        #pragma unroll
        for (int g = 0; g < 16; g++) {
            int rowloc = (g & 3) + 8 * (g >> 2) + 4 * (tid >> 5);
            int il = ti * 32 + rowloc;
            if (jv && il < m && il != jl) {
                float kl = tjv - acc[g] * (1.0f / C_SZ);
                local += kl * kl;
            }
        }
        #pragma unroll
        for (int o = 32; o >= 1; o >>= 1) local += __shfl_xor(local, o, 64);
        if (tid == 0) atomicAdd(accum, local);
    }
}

__global__ void finalize_kernel(const float* __restrict__ accum, float* __restrict__ out) {
    out[0] = accum[0] * (1.0f / B_SZ);
}

extern "C" void kernel_launch(void* const* d_in, const int* in_sizes, int n_in,
                              void* d_out, int out_size, void* d_ws, size_t ws_size,
                              hipStream_t stream) {
    const float* x = (const float*)d_in[0];
    const int* target = (const int*)d_in[1];
    float* out = (float*)d_out;

    char* ws = (char*)d_ws;
    uint32* probs_bf = (uint32*)ws;                                   // 16 MB (B*C bf16)
    char* p = ws + (size_t)B_SZ * C_SZ * 2;
    float* t = (float*)p;            p += B_SZ * 4;                   // 32 KB
    int* counts = (int*)p;           p += 128 * 4;                    // 512 B
    int* nitems = (int*)p;           p += 16;                         // 4 B (+pad)
    int* lists = (int*)p;            p += (size_t)NCLS * B_SZ * 4;    // 3.2 MB
    int* items = (int*)p;            p += 65536 * 4;                  // 256 KB
    float* accum = (float*)p;                                         // 4 B

    init_kernel<<<1, 128, 0, stream>>>(counts, nitems, accum);
    softmax_kernel<<<B_SZ, 256, 0, stream>>>(x, probs_bf, t);
    bucket_kernel<<<B_SZ / 256, 256, 0, stream>>>(target, counts, lists);
    setup_items_kernel<<<1, 128, 0, stream>>>(counts, nitems, items);
    pair_kernel<<<1024, 64, 0, stream>>>((const uint4*)probs_bf, t, counts, lists,
                                         nitems, items, accum);
    finalize_kernel<<<1, 1, 0, stream>>>(accum, out);
}